// Round 9
// baseline (230.284 us; speedup 1.0000x reference)
//
#include <hip/hip_runtime.h>
#include <math.h>

// VQ-VAE quantize: z [8,4096,512] f32, embed_w [1024,512] f32
// out = concat(z_q, diff, ind-as-f32)
//
// bf16 split-precision MFMA:  dot ~= zhi*ehi + zhi*elo + zlo*ehi
// score = ||e||^2 - 2*dot  (row-constant ||z||^2 dropped; argmin invariant)
// gemm: 128x128 tile, 4 waves, 32x32x16 MFMA, BK=16 -> 16KB/buffer ->
// 32KB dbuf -> 4 blocks/CU (4 waves/SIMD TLP). Counted vmcnt(4) across the
// barrier; setprio around MFMA cluster.

#define D_DIM   512
#define K_CODES 1024
#define N_TOK   32768

#define BM 128
#define BN 128
#define NKT 32            // 512 / 16 bf16-cols per k-tile
#define BUFU 8192         // ushorts per buffer (16 KB)

typedef __attribute__((ext_vector_type(8))) short bf16x8;
typedef __attribute__((ext_vector_type(16))) float f32x16;

__device__ __forceinline__ unsigned short bf16_rne(float f) {
    unsigned int u = __float_as_uint(f);
    return (unsigned short)((u + 0x7FFFu + ((u >> 16) & 1u)) >> 16);
}
__device__ __forceinline__ float bf16_to_f32(unsigned short b) {
    return __uint_as_float(((unsigned int)b) << 16);
}

#define GLOAD16(gp, lp)                                                        \
    __builtin_amdgcn_global_load_lds(                                          \
        (const __attribute__((address_space(1))) void*)(gp),                   \
        (__attribute__((address_space(3))) void*)(lp), 16, 0, 0)

// ---------------- z -> zhi/zlo bf16 planes --------------------------------
__global__ __launch_bounds__(256) void vq_zsplit(const float* __restrict__ z,
                                                 unsigned short* __restrict__ zhi,
                                                 unsigned short* __restrict__ zlo) {
    const int tid = blockIdx.x * 256 + threadIdx.x;   // grid 2048
    const float4* z4 = (const float4*)z;
    ushort4* h4 = (ushort4*)zhi;
    ushort4* l4 = (ushort4*)zlo;
#pragma unroll
    for (int g = 0; g < 8; ++g) {
        const size_t i = (size_t)g * 524288 + tid;
        float4 v = z4[i];
        float f[4] = {v.x, v.y, v.z, v.w};
        unsigned short hb[4], lb[4];
#pragma unroll
        for (int j = 0; j < 4; ++j) {
            hb[j] = bf16_rne(f[j]);
            lb[j] = bf16_rne(f[j] - bf16_to_f32(hb[j]));
        }
        h4[i] = make_ushort4(hb[0], hb[1], hb[2], hb[3]);
        l4[i] = make_ushort4(lb[0], lb[1], lb[2], lb[3]);
    }
}

// ---------------- ew -> ehi/elo bf16 + e2 ---------------------------------
__global__ __launch_bounds__(256) void vq_prep(const float* __restrict__ ew,
                                               unsigned short* __restrict__ ehi,
                                               unsigned short* __restrict__ elo,
                                               float* __restrict__ e2) {
    const int wv = threadIdx.x >> 6, lane = threadIdx.x & 63;
    const int code = blockIdx.x * 4 + wv;          // grid 256
    const float* row = ew + (size_t)code * D_DIM;
    float s = 0.0f;
#pragma unroll
    for (int h = 0; h < 2; ++h) {
        const int c = h * 256 + lane * 4;
        float4 v = *(const float4*)(row + c);
        float f[4] = {v.x, v.y, v.z, v.w};
        unsigned short hb[4], lb[4];
#pragma unroll
        for (int j = 0; j < 4; ++j) {
            s = fmaf(f[j], f[j], s);
            hb[j] = bf16_rne(f[j]);
            lb[j] = bf16_rne(f[j] - bf16_to_f32(hb[j]));
        }
        *(ushort4*)(ehi + (size_t)code * D_DIM + c) = make_ushort4(hb[0], hb[1], hb[2], hb[3]);
        *(ushort4*)(elo + (size_t)code * D_DIM + c) = make_ushort4(lb[0], lb[1], lb[2], lb[3]);
    }
#pragma unroll
    for (int off = 32; off > 0; off >>= 1) s += __shfl_xor(s, off, 64);
    if (lane == 0) e2[code] = s;
}

// ---------------- split-GEMM + per-tile argmin (32x32x16, 4 blk/CU) -------
__global__ __launch_bounds__(256, 4) void vq_gemm(
    const unsigned short* __restrict__ zhi, const unsigned short* __restrict__ zlo,
    const unsigned short* __restrict__ ehi, const unsigned short* __restrict__ elo,
    const float* __restrict__ e2, float* __restrict__ pv, float* __restrict__ pif) {
    // 2 buffers x 16 KB; per buffer: 4 planes x [2 kchunks][128 rows] x 16B
    // plane ushort offsets: AHI 0, ALO 2048, BHI 4096, BLO 6144
    __shared__ __align__(16) unsigned short lds[2 * BUFU];

    const int t = threadIdx.x, lane = t & 63, wv = t >> 6;
    // XCD-contiguous swizzle: 2048 wgs, 8 XCDs, 256 each; ntile innermost
    const int b  = blockIdx.x;
    const int wg = (b & 7) * 256 + (b >> 3);
    const int mtile = wg >> 3, ntile = wg & 7;
    const int row0 = mtile * BM;
    const int c0g  = ntile * BN;

    // staging: one 16B slot per plane per thread; slot t: kchunk=t>>7, row=t&127
    const int kc_s = t >> 7;
    const int rr_s = t & 127;
    const size_t zo = (size_t)(row0 + rr_s) * D_DIM + kc_s * 8;
    const size_t eo = (size_t)(c0g + rr_s) * D_DIM + kc_s * 8;
    const int sl = t * 8;          // ushort offset within plane

    const int wr = wv >> 1, wc = wv & 1;       // 2x2 wave grid, 64x64 out each
    const int l31 = lane & 31, kc = lane >> 5; // frag row-in-32 / kchunk

    f32x16 acc[2][2];
#pragma unroll
    for (int i = 0; i < 2; ++i)
#pragma unroll
        for (int j = 0; j < 2; ++j)
#pragma unroll
            for (int r = 0; r < 16; ++r) acc[i][j][r] = 0.0f;

    auto stage = [&](int kt, int bufo) {
        const int ko = kt * 16;
        GLOAD16(zhi + zo + ko, &lds[bufo + 0    + sl]);
        GLOAD16(zlo + zo + ko, &lds[bufo + 2048 + sl]);
        GLOAD16(ehi + eo + ko, &lds[bufo + 4096 + sl]);
        GLOAD16(elo + eo + ko, &lds[bufo + 6144 + sl]);
    };

    auto compute = [&](int bufo) {
        bf16x8 ah[2], al[2], bh[2], bl[2];
#pragma unroll
        for (int mi = 0; mi < 2; ++mi) {
            const int s = (kc * 128 + wr * 64 + mi * 32 + l31) * 8;
            ah[mi] = *(const bf16x8*)&lds[bufo + 0    + s];
            al[mi] = *(const bf16x8*)&lds[bufo + 2048 + s];
        }
#pragma unroll
        for (int nj = 0; nj < 2; ++nj) {
            const int s = (kc * 128 + wc * 64 + nj * 32 + l31) * 8;
            bh[nj] = *(const bf16x8*)&lds[bufo + 4096 + s];
            bl[nj] = *(const bf16x8*)&lds[bufo + 6144 + s];
        }
        __builtin_amdgcn_s_setprio(1);
#pragma unroll
        for (int mi = 0; mi < 2; ++mi)
#pragma unroll
            for (int nj = 0; nj < 2; ++nj)
                acc[mi][nj] = __builtin_amdgcn_mfma_f32_32x32x16_bf16(
                    ah[mi], bh[nj], acc[mi][nj], 0, 0, 0);
#pragma unroll
        for (int mi = 0; mi < 2; ++mi)
#pragma unroll
            for (int nj = 0; nj < 2; ++nj)
                acc[mi][nj] = __builtin_amdgcn_mfma_f32_32x32x16_bf16(
                    ah[mi], bl[nj], acc[mi][nj], 0, 0, 0);
#pragma unroll
        for (int mi = 0; mi < 2; ++mi)
#pragma unroll
            for (int nj = 0; nj < 2; ++nj)
                acc[mi][nj] = __builtin_amdgcn_mfma_f32_32x32x16_bf16(
                    al[mi], bh[nj], acc[mi][nj], 0, 0, 0);
        __builtin_amdgcn_s_setprio(0);
    };

    // prologue: two tiles in flight (8 gloads outstanding)
    stage(0, 0);
    stage(1, BUFU);

    for (int kt = 0; kt < NKT - 1; ++kt) {
        const int bufo = (kt & 1) * BUFU;
        asm volatile("s_waitcnt vmcnt(4)" ::: "memory");   // tile kt landed
        __builtin_amdgcn_s_barrier();                      // all waves agree
        __builtin_amdgcn_sched_barrier(0);
        compute(bufo);
        __builtin_amdgcn_sched_barrier(0);
        __builtin_amdgcn_s_barrier();                      // reads of bufo done
        if (kt + 2 < NKT) stage(kt + 2, bufo);             // refill this buffer
    }
    {   // peeled last tile: drain fully
        const int bufo = ((NKT - 1) & 1) * BUFU;
        asm volatile("s_waitcnt vmcnt(0)" ::: "memory");
        __builtin_amdgcn_s_barrier();
        __builtin_amdgcn_sched_barrier(0);
        compute(bufo);
    }

    // ---- epilogue: score + per-row argmin over this 128-code tile ----
    // 32x32x16 C/D mapping (m74/m101): col=lane&31, row=(reg&3)+8*(reg>>2)+4*(lane>>5)
    __syncthreads();                 // all compute done; lds reusable
    float* sv = (float*)lds;         // [2][128]
    float* si = sv + 256;
#pragma unroll
    for (int mi = 0; mi < 2; ++mi) {
        float best[16], bidx[16];
#pragma unroll
        for (int r = 0; r < 16; ++r) { best[r] = INFINITY; bidx[r] = 0.f; }
#pragma unroll
        for (int nj = 0; nj < 2; ++nj) {
            const int cloc = wc * 64 + nj * 32 + l31;
            const float e2v = e2[c0g + cloc];
            const float cif = (float)(c0g + cloc);
#pragma unroll
            for (int r = 0; r < 16; ++r) {
                const float sc = fmaf(-2.0f, acc[mi][nj][r], e2v);
                if (sc < best[r]) { best[r] = sc; bidx[r] = cif; }
            }
        }
        // reduce across the 32 lanes (l31) sharing each row; lexicographic
#pragma unroll
        for (int off = 1; off < 32; off <<= 1) {
#pragma unroll
            for (int r = 0; r < 16; ++r) {
                float v2 = __shfl_xor(best[r], off, 64);
                float i2 = __shfl_xor(bidx[r], off, 64);
                if (v2 < best[r] || (v2 == best[r] && i2 < bidx[r])) {
                    best[r] = v2; bidx[r] = i2;
                }
            }
        }
        if (l31 == 0) {
            const int hi4 = kc * 4;    // 4*(lane>>5)
#pragma unroll
            for (int r = 0; r < 16; ++r) {
                const int rloc = wr * 64 + mi * 32 + (r & 3) + 8 * (r >> 2) + hi4;
                sv[wc * 128 + rloc] = best[r];
                si[wc * 128 + rloc] = bidx[r];
            }
        }
    }
    __syncthreads();
    if (t < 128) {
        float v0 = sv[t], i0 = si[t];
        float v1 = sv[128 + t], i1 = si[128 + t];
        if (v1 < v0 || (v1 == v0 && i1 < i0)) { v0 = v1; i0 = i1; }
        pv [(size_t)ntile * N_TOK + row0 + t] = v0;
        pif[(size_t)ntile * N_TOK + row0 + t] = i0;
    }
}

// ---------------- outputs: fused 8-tile argmin + z_q, diff, ind -----------
__global__ __launch_bounds__(256) void vq_out_kernel(
    const float* __restrict__ z, const float* __restrict__ ew,
    const float* __restrict__ pv, const float* __restrict__ pif,
    float* __restrict__ indf, float* __restrict__ zq, float* __restrict__ diff) {
    const int w    = threadIdx.x >> 6;
    const int lane = threadIdx.x & 63;
    const int row  = blockIdx.x * 4 + w;

    // reduce the 8 n-tile partials (ascending -> first-min semantics)
    float v = INFINITY, ix = 0.f;
    if (lane < 8) {
        v  = pv [(size_t)lane * N_TOK + row];
        ix = pif[(size_t)lane * N_TOK + row];
    }
#pragma unroll
    for (int off = 1; off < 8; off <<= 1) {
        float v2 = __shfl_xor(v, off, 64);
        float i2 = __shfl_xor(ix, off, 64);
        if (v2 < v || (v2 == v && i2 < ix)) { v = v2; ix = i2; }
    }
    const float ixb = __shfl(ix, 0, 64);
    const int c = (int)ixb;
    if (lane == 0) indf[row] = ixb;

    const float4* z4 = (const float4*)&z[(size_t)row * D_DIM];
    const float4* e4 = (const float4*)&ew[(size_t)c * D_DIM];
    float4* q4 = (float4*)&zq[(size_t)row * D_DIM];
    float4* d4 = (float4*)&diff[(size_t)row * D_DIM];

#pragma unroll
    for (int vv = 0; vv < 2; ++vv) {
        const int i = vv * 64 + lane;
        const float4 zv = z4[i];
        const float4 ev = e4[i];
        float4 qv, dv;
        float ax = ev.x - zv.x, ay = ev.y - zv.y, az = ev.z - zv.z, aw = ev.w - zv.w;
        qv.x = zv.x + ax; qv.y = zv.y + ay; qv.z = zv.z + az; qv.w = zv.w + aw;
        dv.x = 0.5f * (ax * ax); dv.y = 0.5f * (ay * ay);
        dv.z = 0.5f * (az * az); dv.w = 0.5f * (aw * aw);
        q4[i] = qv;
        d4[i] = dv;
    }
}

extern "C" void kernel_launch(void* const* d_in, const int* in_sizes, int n_in,
                              void* d_out, int out_size, void* d_ws, size_t ws_size,
                              hipStream_t stream) {
    const float* z  = (const float*)d_in[0];
    const float* ew = (const float*)d_in[1];
    float* out  = (float*)d_out;
    float* zq   = out;
    float* diff = out + (size_t)N_TOK * D_DIM;
    float* indf = out + (size_t)2 * N_TOK * D_DIM;

    // scratch: ehi/elo/e2 in zq region (gemm reads them; out-kernel writes zq
    // only after); zhi/zlo in diff region; pv/pif in d_ws.
    char* s0 = (char*)d_out;
    unsigned short* ehi = (unsigned short*)(s0);                   // 1 MB
    unsigned short* elo = (unsigned short*)(s0 + (1u << 20));      // 1 MB
    float* e2  = (float*)(s0 + (2u << 20));                        // 4 KB
    unsigned short* zhi = (unsigned short*)diff;                   // 32 MB
    unsigned short* zlo = zhi + (size_t)N_TOK * D_DIM;             // 32 MB
    float* pv  = (float*)d_ws;                                     // 1 MB
    float* pif = (float*)d_ws + (size_t)8 * N_TOK;                 // 1 MB

    hipLaunchKernelGGL(vq_zsplit, dim3(2048),        dim3(256), 0, stream, z, zhi, zlo);
    hipLaunchKernelGGL(vq_prep,   dim3(K_CODES / 4), dim3(256), 0, stream, ew, ehi, elo, e2);
    hipLaunchKernelGGL(vq_gemm,   dim3(2048),        dim3(256), 0, stream,
                       zhi, zlo, ehi, elo, e2, pv, pif);
    hipLaunchKernelGGL(vq_out_kernel, dim3(N_TOK / 4), dim3(256), 0, stream,
                       z, ew, pv, pif, indf, zq, diff);
}